// Round 9
// baseline (155.025 us; speedup 1.0000x reference)
//
#include <hip/hip_runtime.h>

// LightGCN extractor, round 9:
//  - build: two-level counting sort, all global writes dense (R8)
//  - k_sort secondary key = column slice (8 x 18752 cols) -> concurrent gathers
//    hit a ~2.3MB L2-resident window; row grouping unchanged
//  - gathers: masked always-8 batch per row (no serial tail; deg mean = 8)
//  NOTE: float atomicAdd on __shared__ is a slow generic path (~8000cy, R7) - avoid.

#define STU 100000
#define EXER 50000
#define KNOW 123
#define DIM 64
#define N_NODES 150000
#define N_EDGES 1200000
#define NB 8192
#define BR 256                 // rows per bucket
#define NBUCK 586              // ceil(150000/256)
#define PB 256                 // partition blocks
#define EPB 4688               // ceil(N_EDGES/PB)
#define NSB 586                // scan blocks over NBUCK*PB = 150016
#define SCAP 2816              // max edges per bucket (mean 2048, sigma ~45 -> +17σ)
#define NKEY 2048              // 256 rows x 8 col-slices

typedef unsigned short bfu;

__device__ __forceinline__ bfu f2bf(float f) {
    unsigned int u = __float_as_uint(f);
    unsigned int r = (u + 0x7FFFu + ((u >> 16) & 1u)) >> 16;   // RNE
    return (bfu)r;
}
__device__ __forceinline__ float bf2f(bfu h) {
    return __uint_as_float((unsigned int)h << 16);
}
__device__ __forceinline__ int colslice(unsigned c) {          // c/18752, clamped to 7
    int s = (int)(((unsigned long long)c * 229065ull) >> 32);
    return s > 7 ? 7 : s;
}

// ---- h0 concat -> bf16 table ----
__global__ void k_conv0(const float* __restrict__ stu, const float* __restrict__ exer,
                        bfu* __restrict__ b0) {
    long long i = (long long)blockIdx.x * blockDim.x + threadIdx.x;  // float4 index
    long long n4 = ((long long)N_NODES * DIM) >> 2;
    if (i >= n4) return;
    long long stu4 = ((long long)STU * DIM) >> 2;
    float4 v = (i < stu4) ? ((const float4*)stu)[i]
                          : ((const float4*)exer)[i - stu4];
    ushort4 o;
    o.x = f2bf(v.x); o.y = f2bf(v.y); o.z = f2bf(v.z); o.w = f2bf(v.w);
    ((ushort4*)b0)[i] = o;
}

// ---- bucket counts: gcounts[bucket*PB + block] ----
__global__ __launch_bounds__(1024) void k_count(const int* __restrict__ erow,
                                                int* __restrict__ gcounts) {
    __shared__ int cnt[NBUCK];
    for (int i = threadIdx.x; i < NBUCK; i += 1024) cnt[i] = 0;
    __syncthreads();
    int b = blockIdx.x;
    long long s = (long long)b * EPB;
    long long e = s + EPB; if (e > N_EDGES) e = N_EDGES;
    for (long long k = s + threadIdx.x; k < e; k += 1024)
        atomicAdd(&cnt[__builtin_nontemporal_load(&erow[k]) >> 8], 1);
    __syncthreads();
    for (int i = threadIdx.x; i < NBUCK; i += 1024) gcounts[i * PB + b] = cnt[i];
}

// ---- hierarchical exclusive scan over 150016 ints ----
__global__ void k_scan1(const int* __restrict__ gin, int* __restrict__ gout,
                        int* __restrict__ bsum) {
    __shared__ int s[256];
    int i = blockIdx.x * 256 + threadIdx.x;
    int v = gin[i];
    s[threadIdx.x] = v;
    __syncthreads();
    for (int o = 1; o < 256; o <<= 1) {
        int x = (threadIdx.x >= o) ? s[threadIdx.x - o] : 0;
        __syncthreads();
        s[threadIdx.x] += x;
        __syncthreads();
    }
    gout[i] = s[threadIdx.x] - v;
    if (threadIdx.x == 255) bsum[blockIdx.x] = s[255];
}

__global__ void k_scan2(const int* __restrict__ bsum, int* __restrict__ bsumoff) {
    __shared__ int s[1024];
    int t = threadIdx.x;
    int v = (t < NSB) ? bsum[t] : 0;
    s[t] = v;
    __syncthreads();
    for (int o = 1; o < 1024; o <<= 1) {
        int x = (t >= o) ? s[t - o] : 0;
        __syncthreads();
        s[t] += x;
        __syncthreads();
    }
    if (t < NSB) bsumoff[t] = s[t] - v;
}

__global__ void k_scan3(int* __restrict__ gout, const int* __restrict__ bsumoff,
                        int* __restrict__ boff) {
    int i = blockIdx.x * 256 + threadIdx.x;
    int v = gout[i] + bsumoff[i >> 8];
    gout[i] = v;
    if ((i & 255) == 0) boff[i >> 8] = v;   // PB==256: bucket start
    if (i == 0) boff[NBUCK] = N_EDGES;
}

// ---- place: block-local LDS counting sort by bucket, dense run writes ----
__global__ __launch_bounds__(1024) void k_place(const int* __restrict__ erow,
                                                const int* __restrict__ ecol,
                                                const float* __restrict__ eval,
                                                const int* __restrict__ gscan,
                                                int2* __restrict__ bedge) {
    __shared__ int2 staged[EPB];            // 37504 B
    __shared__ unsigned short sbkt[EPB];    // 9376 B
    __shared__ int lbase[NBUCK];
    __shared__ int lcur[NBUCK];
    __shared__ int gbase[NBUCK];
    __shared__ int stmp[1024];
    int b = blockIdx.x, tid = threadIdx.x;
    for (int i = tid; i < NBUCK; i += 1024) lcur[i] = 0;
    __syncthreads();
    long long s = (long long)b * EPB;
    long long e = s + EPB; if (e > N_EDGES) e = N_EDGES;
    int n = (int)(e - s);
    for (int k = tid; k < n; k += 1024)
        atomicAdd(&lcur[__builtin_nontemporal_load(&erow[s + k]) >> 8], 1);
    __syncthreads();
    int v = (tid < NBUCK) ? lcur[tid] : 0;
    stmp[tid] = v;
    __syncthreads();
    for (int o = 1; o < 1024; o <<= 1) {
        int x = (tid >= o) ? stmp[tid - o] : 0;
        __syncthreads();
        stmp[tid] += x;
        __syncthreads();
    }
    if (tid < NBUCK) { lbase[tid] = stmp[tid] - v; lcur[tid] = stmp[tid] - v; }
    for (int i = tid; i < NBUCK; i += 1024) gbase[i] = gscan[i * PB + b];
    __syncthreads();
    for (int k = tid; k < n; k += 1024) {
        int r = __builtin_nontemporal_load(&erow[s + k]);
        int c = __builtin_nontemporal_load(&ecol[s + k]);
        float vv = __builtin_nontemporal_load(&eval[s + k]);
        int bk = r >> 8;
        int p = atomicAdd(&lcur[bk], 1);
        staged[p] = make_int2((r & 255) | (c << 8), __float_as_int(vv));
        sbkt[p] = (unsigned short)bk;
    }
    __syncthreads();
    for (int t = tid; t < n; t += 1024) {
        int bk = sbkt[t];
        bedge[gbase[bk] + (t - lbase[bk])] = staged[t];
    }
}

// ---- per-bucket LDS counting sort: key = (localrow<<3)|colslice ----
__global__ __launch_bounds__(512) void k_sort(const int* __restrict__ boff,
                                              const int2* __restrict__ bedge,
                                              int2* __restrict__ sedge,
                                              int* __restrict__ off) {
    __shared__ int2 st[SCAP];      // 22528 B
    __shared__ int2 st2[SCAP];     // 22528 B
    __shared__ int hist[NKEY];     // 8192 B
    __shared__ int cur[NKEY];      // 8192 B
    __shared__ int stmp[512];      // 2048 B   (total 63488 B)
    int b = blockIdx.x, tid = threadIdx.x;
    int s = boff[b], e = boff[b + 1];
    int n = e - s; if (n > SCAP) n = SCAP;   // statistically unreachable
    for (int i = tid; i < NKEY; i += 512) hist[i] = 0;
    __syncthreads();
    for (int t = tid; t < n; t += 512) {
        int2 ev = bedge[s + t];
        st[t] = ev;
        int key = ((ev.x & 255) << 3) | colslice((unsigned)ev.x >> 8);
        atomicAdd(&hist[key], 1);
    }
    __syncthreads();
    // scan 2048 hist entries: 4 per thread
    int v4[4]; int sum = 0;
#pragma unroll
    for (int j = 0; j < 4; j++) { v4[j] = hist[tid * 4 + j]; sum += v4[j]; }
    stmp[tid] = sum;
    __syncthreads();
    for (int o = 1; o < 512; o <<= 1) {
        int x = (tid >= o) ? stmp[tid - o] : 0;
        __syncthreads();
        stmp[tid] += x;
        __syncthreads();
    }
    int ex = stmp[tid] - sum;
#pragma unroll
    for (int j = 0; j < 4; j++) {
        int key = tid * 4 + j;
        cur[key] = ex;
        if ((key & 7) == 0) off[b * BR + (key >> 3)] = s + ex;  // row start
        ex += v4[j];
    }
    __syncthreads();
    for (int t = tid; t < n; t += 512) {
        int2 ev = st[t];
        int key = ((ev.x & 255) << 3) | colslice((unsigned)ev.x >> 8);
        int p = atomicAdd(&cur[key], 1);
        st2[p] = make_int2((unsigned)ev.x >> 8, ev.y);   // (col, valbits)
    }
    __syncthreads();
    for (int t = tid; t < n; t += 512) sedge[s + t] = st2[t];
}

// ---- gather layer: wave per node, masked always-8 batch ----
__global__ void k_gather_bf(const int* __restrict__ off, const int2* __restrict__ sedge,
                            const bfu* __restrict__ h, bfu* __restrict__ out) {
    int w = (blockIdx.x * blockDim.x + threadIdx.x) >> 6;
    int lane = threadIdx.x & 63;
    if (w >= N_NODES) return;
    int wu = __builtin_amdgcn_readfirstlane(w);
    int s = off[wu], e = off[wu + 1];
    float acc = 0.f;
    for (int k = s; k < e; k += 8) {
        int2 ev[8]; float wgt[8];
#pragma unroll
        for (int j = 0; j < 8; j++) {
            int idx = (k + j < e) ? (k + j) : (e - 1);
            ev[j] = sedge[idx];
            wgt[j] = (k + j < e) ? __int_as_float(ev[j].y) : 0.f;
        }
        float a[8];
#pragma unroll
        for (int j = 0; j < 8; j++) a[j] = bf2f(h[(size_t)ev[j].x * DIM + lane]);
#pragma unroll
        for (int j = 0; j < 8; j++) acc += wgt[j] * a[j];
    }
    out[(size_t)wu * DIM + lane] = f2bf(acc);
}

// ---- outputs: layer-3 gather over B2 fused, only the 16K needed rows ----
// out layout: [0,524288) student_ts | [524288,1048576) diff_ts
//             [1048576,1056768) disc | [1056768,1064640) know
__global__ void k_out_main(const int* __restrict__ sid, const int* __restrict__ eid,
                           const int* __restrict__ off, const int2* __restrict__ sedge,
                           const float* __restrict__ stu, const float* __restrict__ exer,
                           const bfu* __restrict__ B1, const bfu* __restrict__ B2,
                           float* __restrict__ out) {
    int w = (blockIdx.x * blockDim.x + threadIdx.x) >> 6;
    int lane = threadIdx.x & 63;
    if (w >= 2 * NB) return;
    int wu = __builtin_amdgcn_readfirstlane(w);
    int r;
    long long obase;
    if (wu < NB) { r = sid[wu];            obase = (long long)wu * 64; }
    else         { r = STU + eid[wu - NB]; obase = 524288 + (long long)(wu - NB) * 64; }
    int ru = __builtin_amdgcn_readfirstlane(r);
    long long rb = (long long)ru * 64 + lane;
    float h0 = (ru < STU) ? stu[rb] : exer[rb - (long long)STU * 64];
    float ssum = h0 + bf2f(B1[rb]) + bf2f(B2[rb]);
    int st = off[ru], en = off[ru + 1];
    float g = 0.f;
    for (int k = st; k < en; k += 8) {
        int2 ev[8]; float wgt[8];
#pragma unroll
        for (int j = 0; j < 8; j++) {
            int idx = (k + j < en) ? (k + j) : (en - 1);
            ev[j] = sedge[idx];
            wgt[j] = (k + j < en) ? __int_as_float(ev[j].y) : 0.f;
        }
        float a[8];
#pragma unroll
        for (int j = 0; j < 8; j++) a[j] = bf2f(B2[(size_t)ev[j].x * DIM + lane]);
#pragma unroll
        for (int j = 0; j < 8; j++) g += wgt[j] * a[j];
    }
    out[obase + lane] = 0.25f * (ssum + g);
}

__global__ void k_out_tail(const int* __restrict__ eid, const float* __restrict__ disc,
                           const float* __restrict__ know, float* __restrict__ out) {
    int i = blockIdx.x * blockDim.x + threadIdx.x;
    if (i < NB) out[1048576 + i] = disc[eid[i]];
    else if (i < NB + KNOW * DIM) out[1056768 + (i - NB)] = know[i - NB];
}

extern "C" void kernel_launch(void* const* d_in, const int* in_sizes, int n_in,
                              void* d_out, int out_size, void* d_ws, size_t ws_size,
                              hipStream_t stream) {
    const int*   sid  = (const int*)d_in[0];
    const int*   eid  = (const int*)d_in[1];
    const int*   erow = (const int*)d_in[3];
    const int*   ecol = (const int*)d_in[4];
    const float* eval = (const float*)d_in[5];
    const float* stu  = (const float*)d_in[6];
    const float* exer = (const float*)d_in[7];
    const float* disc = (const float*)d_in[8];
    const float* know = (const float*)d_in[9];
    float* out = (float*)d_out;

    char* ws = (char*)d_ws;
    bfu*  B0      = (bfu*) (ws);                          // 19,200,000
    bfu*  B1      = (bfu*) (ws + 19200000);               // 19,200,000
    bfu*  B2      = (bfu*) (ws + 38400000);               // 19,200,000
    int2* bedge   = (int2*)(ws + 57600000);               // 9,600,000 (bucket-sorted)
    int2* sedge   = (int2*)(ws + 67200000);               // 9,600,000 (row+slice-sorted)
    int*  gcounts = (int*) (ws + 76800000);               // 600,064
    int*  gscan   = (int*) (ws + 77400064);               // 600,064
    int*  bsum    = (int*) (ws + 78000128);               // 2,560
    int*  bsumoff = (int*) (ws + 78002688);               // 2,560
    int*  boff    = (int*) (ws + 78005248);               // 2,348
    int*  off     = (int*) (ws + 78007596);               // 600,064 (ends ~78.6 MB)

    const int BLK = 256;
    long long n4 = ((long long)N_NODES * DIM) >> 2;
    int convGrid = (int)((n4 + BLK - 1) / BLK);
    int nodeWaveGrid = (int)(((long long)N_NODES * 64 + BLK - 1) / BLK);  // 37500
    int outMainGrid = (2 * NB * 64) / BLK;
    int outTailGrid = (NB + KNOW * DIM + BLK - 1) / BLK;

    // h0 -> bf16 table
    k_conv0<<<convGrid, BLK, 0, stream>>>(stu, exer, B0);

    // two-level counting sort (all writes dense)
    k_count<<<PB, 1024, 0, stream>>>(erow, gcounts);
    k_scan1<<<NSB, 256, 0, stream>>>(gcounts, gscan, bsum);
    k_scan2<<<1, 1024, 0, stream>>>(bsum, bsumoff);
    k_scan3<<<NSB, 256, 0, stream>>>(gscan, bsumoff, boff);
    k_place<<<PB, 1024, 0, stream>>>(erow, ecol, eval, gscan, bedge);
    k_sort <<<NBUCK, 512, 0, stream>>>(boff, bedge, sedge, off);

    // layers 1,2
    k_gather_bf<<<nodeWaveGrid, BLK, 0, stream>>>(off, sedge, B0, B1);
    k_gather_bf<<<nodeWaveGrid, BLK, 0, stream>>>(off, sedge, B1, B2);

    // layer 3 fused into outputs
    k_out_main<<<outMainGrid, BLK, 0, stream>>>(sid, eid, off, sedge, stu, exer, B1, B2, out);
    k_out_tail<<<outTailGrid, BLK, 0, stream>>>(eid, disc, know, out);
}

// Round 10
// 120.645 us; speedup vs baseline: 1.2850x; 1.2850x over previous
//
#include <hip/hip_runtime.h>

// LightGCN extractor, round 10:
//  - build: R8's two-level counting sort (all global writes dense) - unchanged
//  - gathers: 2 rows per wave (half-wave split, u32 bf16x2 per lane) ->
//    2x memory-level parallelism, half the waves, half the VMEM instructions
//  - layer 3 fused into output kernel (R8 version)
//  NOTE: float atomicAdd on __shared__ is a slow generic path (~8000cy, R7) - avoid.

#define STU 100000
#define EXER 50000
#define KNOW 123
#define DIM 64
#define N_NODES 150000
#define N_EDGES 1200000
#define NB 8192
#define BR 256                 // rows per bucket
#define NBUCK 586              // ceil(150000/256)
#define PB 256                 // partition blocks
#define EPB 4688               // ceil(N_EDGES/PB)
#define NSB 586                // scan blocks over NBUCK*PB = 150016
#define SCAP 3072              // max edges per bucket (mean 2048)

typedef unsigned short bfu;

__device__ __forceinline__ bfu f2bf(float f) {
    unsigned int u = __float_as_uint(f);
    unsigned int r = (u + 0x7FFFu + ((u >> 16) & 1u)) >> 16;   // RNE
    return (bfu)r;
}
__device__ __forceinline__ float bf2f(bfu h) {
    return __uint_as_float((unsigned int)h << 16);
}

// ---- h0 concat -> bf16 table ----
__global__ void k_conv0(const float* __restrict__ stu, const float* __restrict__ exer,
                        bfu* __restrict__ b0) {
    long long i = (long long)blockIdx.x * blockDim.x + threadIdx.x;  // float4 index
    long long n4 = ((long long)N_NODES * DIM) >> 2;
    if (i >= n4) return;
    long long stu4 = ((long long)STU * DIM) >> 2;
    float4 v = (i < stu4) ? ((const float4*)stu)[i]
                          : ((const float4*)exer)[i - stu4];
    ushort4 o;
    o.x = f2bf(v.x); o.y = f2bf(v.y); o.z = f2bf(v.z); o.w = f2bf(v.w);
    ((ushort4*)b0)[i] = o;
}

// ---- bucket counts: gcounts[bucket*PB + block] ----
__global__ __launch_bounds__(1024) void k_count(const int* __restrict__ erow,
                                                int* __restrict__ gcounts) {
    __shared__ int cnt[NBUCK];
    for (int i = threadIdx.x; i < NBUCK; i += 1024) cnt[i] = 0;
    __syncthreads();
    int b = blockIdx.x;
    long long s = (long long)b * EPB;
    long long e = s + EPB; if (e > N_EDGES) e = N_EDGES;
    for (long long k = s + threadIdx.x; k < e; k += 1024)
        atomicAdd(&cnt[__builtin_nontemporal_load(&erow[k]) >> 8], 1);
    __syncthreads();
    for (int i = threadIdx.x; i < NBUCK; i += 1024) gcounts[i * PB + b] = cnt[i];
}

// ---- hierarchical exclusive scan over 150016 ints ----
__global__ void k_scan1(const int* __restrict__ gin, int* __restrict__ gout,
                        int* __restrict__ bsum) {
    __shared__ int s[256];
    int i = blockIdx.x * 256 + threadIdx.x;
    int v = gin[i];
    s[threadIdx.x] = v;
    __syncthreads();
    for (int o = 1; o < 256; o <<= 1) {
        int x = (threadIdx.x >= o) ? s[threadIdx.x - o] : 0;
        __syncthreads();
        s[threadIdx.x] += x;
        __syncthreads();
    }
    gout[i] = s[threadIdx.x] - v;
    if (threadIdx.x == 255) bsum[blockIdx.x] = s[255];
}

__global__ void k_scan2(const int* __restrict__ bsum, int* __restrict__ bsumoff) {
    __shared__ int s[1024];
    int t = threadIdx.x;
    int v = (t < NSB) ? bsum[t] : 0;
    s[t] = v;
    __syncthreads();
    for (int o = 1; o < 1024; o <<= 1) {
        int x = (t >= o) ? s[t - o] : 0;
        __syncthreads();
        s[t] += x;
        __syncthreads();
    }
    if (t < NSB) bsumoff[t] = s[t] - v;
}

__global__ void k_scan3(int* __restrict__ gout, const int* __restrict__ bsumoff,
                        int* __restrict__ boff) {
    int i = blockIdx.x * 256 + threadIdx.x;
    int v = gout[i] + bsumoff[i >> 8];
    gout[i] = v;
    if ((i & 255) == 0) boff[i >> 8] = v;   // PB==256: bucket start
    if (i == 0) boff[NBUCK] = N_EDGES;
}

// ---- place: block-local LDS counting sort by bucket, dense run writes ----
__global__ __launch_bounds__(1024) void k_place(const int* __restrict__ erow,
                                                const int* __restrict__ ecol,
                                                const float* __restrict__ eval,
                                                const int* __restrict__ gscan,
                                                int2* __restrict__ bedge) {
    __shared__ int2 staged[EPB];            // 37504 B
    __shared__ unsigned short sbkt[EPB];    // 9376 B
    __shared__ int lbase[NBUCK];
    __shared__ int lcur[NBUCK];
    __shared__ int gbase[NBUCK];
    __shared__ int stmp[1024];
    int b = blockIdx.x, tid = threadIdx.x;
    for (int i = tid; i < NBUCK; i += 1024) lcur[i] = 0;
    __syncthreads();
    long long s = (long long)b * EPB;
    long long e = s + EPB; if (e > N_EDGES) e = N_EDGES;
    int n = (int)(e - s);
    for (int k = tid; k < n; k += 1024)
        atomicAdd(&lcur[__builtin_nontemporal_load(&erow[s + k]) >> 8], 1);
    __syncthreads();
    int v = (tid < NBUCK) ? lcur[tid] : 0;
    stmp[tid] = v;
    __syncthreads();
    for (int o = 1; o < 1024; o <<= 1) {
        int x = (tid >= o) ? stmp[tid - o] : 0;
        __syncthreads();
        stmp[tid] += x;
        __syncthreads();
    }
    if (tid < NBUCK) { lbase[tid] = stmp[tid] - v; lcur[tid] = stmp[tid] - v; }
    for (int i = tid; i < NBUCK; i += 1024) gbase[i] = gscan[i * PB + b];
    __syncthreads();
    for (int k = tid; k < n; k += 1024) {
        int r = __builtin_nontemporal_load(&erow[s + k]);
        int c = __builtin_nontemporal_load(&ecol[s + k]);
        float vv = __builtin_nontemporal_load(&eval[s + k]);
        int bk = r >> 8;
        int p = atomicAdd(&lcur[bk], 1);
        staged[p] = make_int2((r & 255) | (c << 8), __float_as_int(vv));
        sbkt[p] = (unsigned short)bk;
    }
    __syncthreads();
    for (int t = tid; t < n; t += 1024) {
        int bk = sbkt[t];
        bedge[gbase[bk] + (t - lbase[bk])] = staged[t];
    }
}

// ---- per-bucket LDS counting sort by row -> row-sorted edges + off[] ----
__global__ __launch_bounds__(512) void k_sort(const int* __restrict__ boff,
                                              const int2* __restrict__ bedge,
                                              int2* __restrict__ sedge,
                                              int* __restrict__ off) {
    __shared__ int2 st[SCAP];      // 24 KB
    __shared__ int2 st2[SCAP];     // 24 KB
    __shared__ int hist[BR];
    __shared__ int cur[BR];
    __shared__ int stmp[512];
    int b = blockIdx.x, tid = threadIdx.x;
    int s = boff[b], e = boff[b + 1];
    int n = e - s; if (n > SCAP) n = SCAP;   // statistically unreachable
    for (int i = tid; i < BR; i += 512) hist[i] = 0;
    __syncthreads();
    for (int t = tid; t < n; t += 512) {
        int2 ev = bedge[s + t];
        st[t] = ev;
        atomicAdd(&hist[ev.x & 255], 1);
    }
    __syncthreads();
    int v = (tid < BR) ? hist[tid] : 0;
    stmp[tid] = v;
    __syncthreads();
    for (int o = 1; o < 512; o <<= 1) {
        int x = (tid >= o) ? stmp[tid - o] : 0;
        __syncthreads();
        stmp[tid] += x;
        __syncthreads();
    }
    if (tid < BR) {
        int ex = stmp[tid] - v;
        cur[tid] = ex;
        off[b * BR + tid] = s + ex;    // global row offset
    }
    __syncthreads();
    for (int t = tid; t < n; t += 512) {
        int2 ev = st[t];
        int p = atomicAdd(&cur[ev.x & 255], 1);
        st2[p] = make_int2((unsigned)ev.x >> 8, ev.y);   // (col, valbits)
    }
    __syncthreads();
    for (int t = tid; t < n; t += 512) sedge[s + t] = st2[t];
}

// ---- gather layer: 2 rows per wave (half-wave split), u32 bf16x2 per lane ----
__global__ void k_gather2(const int* __restrict__ off, const int2* __restrict__ sedge,
                          const bfu* __restrict__ h, bfu* __restrict__ out) {
    int w = (blockIdx.x * blockDim.x + threadIdx.x) >> 6;   // wave id
    if (w >= N_NODES / 2) return;                           // 75000 waves
    int lane = threadIdx.x & 63;
    int half = lane >> 5, l32 = lane & 31;
    int r0 = __builtin_amdgcn_readfirstlane(w) * 2;
    int o0 = off[r0], o1 = off[r0 + 1], o2 = off[r0 + 2];   // scalar loads
    int s = half ? o1 : o0;
    int e = half ? o2 : o1;
    int dA = o1 - o0, dB = o2 - o1;
    int nmax = dA > dB ? dA : dB;                           // wave-uniform
    const unsigned* h32 = (const unsigned*)h;
    float acc0 = 0.f, acc1 = 0.f;
    for (int j = 0; j < nmax; j += 8) {
        int2 ev[8]; float wg[8];
#pragma unroll
        for (int q = 0; q < 8; q++) {
            int kk = s + j + q;
            int idx = (kk < e) ? kk : 0;                    // clamped: weight 0 below
            ev[q] = sedge[idx];
            wg[q] = (kk < e) ? __int_as_float(ev[q].y) : 0.f;
        }
        unsigned hv[8];
#pragma unroll
        for (int q = 0; q < 8; q++) hv[q] = h32[(size_t)ev[q].x * 32 + l32];
#pragma unroll
        for (int q = 0; q < 8; q++) {
            acc0 += wg[q] * __uint_as_float(hv[q] << 16);
            acc1 += wg[q] * __uint_as_float(hv[q] & 0xffff0000u);
        }
    }
    unsigned o = (unsigned)f2bf(acc0) | ((unsigned)f2bf(acc1) << 16);
    ((unsigned*)out)[(size_t)(r0 + half) * 32 + l32] = o;
}

// ---- outputs: layer-3 gather over B2 fused, only the 16K needed rows ----
// out layout: [0,524288) student_ts | [524288,1048576) diff_ts
//             [1048576,1056768) disc | [1056768,1064640) know
__global__ void k_out_main(const int* __restrict__ sid, const int* __restrict__ eid,
                           const int* __restrict__ off, const int2* __restrict__ sedge,
                           const float* __restrict__ stu, const float* __restrict__ exer,
                           const bfu* __restrict__ B1, const bfu* __restrict__ B2,
                           float* __restrict__ out) {
    int w = (blockIdx.x * blockDim.x + threadIdx.x) >> 6;
    int lane = threadIdx.x & 63;
    if (w >= 2 * NB) return;
    int wu = __builtin_amdgcn_readfirstlane(w);
    int r;
    long long obase;
    if (wu < NB) { r = sid[wu];            obase = (long long)wu * 64; }
    else         { r = STU + eid[wu - NB]; obase = 524288 + (long long)(wu - NB) * 64; }
    int ru = __builtin_amdgcn_readfirstlane(r);
    long long rb = (long long)ru * 64 + lane;
    float h0 = (ru < STU) ? stu[rb] : exer[rb - (long long)STU * 64];
    float ssum = h0 + bf2f(B1[rb]) + bf2f(B2[rb]);
    int st = off[ru], en = off[ru + 1];
    float g = 0.f;
    int k = st;
    for (; k + 8 <= en; k += 8) {
        int2 ev[8];
#pragma unroll
        for (int j = 0; j < 8; j++) ev[j] = sedge[k + j];
        float a[8];
#pragma unroll
        for (int j = 0; j < 8; j++) a[j] = bf2f(B2[(size_t)ev[j].x * DIM + lane]);
#pragma unroll
        for (int j = 0; j < 8; j++) g += __int_as_float(ev[j].y) * a[j];
    }
    for (; k < en; k++) {
        int2 ev = sedge[k];
        g += __int_as_float(ev.y) * bf2f(B2[(size_t)ev.x * DIM + lane]);
    }
    out[obase + lane] = 0.25f * (ssum + g);
}

__global__ void k_out_tail(const int* __restrict__ eid, const float* __restrict__ disc,
                           const float* __restrict__ know, float* __restrict__ out) {
    int i = blockIdx.x * blockDim.x + threadIdx.x;
    if (i < NB) out[1048576 + i] = disc[eid[i]];
    else if (i < NB + KNOW * DIM) out[1056768 + (i - NB)] = know[i - NB];
}

extern "C" void kernel_launch(void* const* d_in, const int* in_sizes, int n_in,
                              void* d_out, int out_size, void* d_ws, size_t ws_size,
                              hipStream_t stream) {
    const int*   sid  = (const int*)d_in[0];
    const int*   eid  = (const int*)d_in[1];
    const int*   erow = (const int*)d_in[3];
    const int*   ecol = (const int*)d_in[4];
    const float* eval = (const float*)d_in[5];
    const float* stu  = (const float*)d_in[6];
    const float* exer = (const float*)d_in[7];
    const float* disc = (const float*)d_in[8];
    const float* know = (const float*)d_in[9];
    float* out = (float*)d_out;

    char* ws = (char*)d_ws;
    bfu*  B0      = (bfu*) (ws);                          // 19,200,000
    bfu*  B1      = (bfu*) (ws + 19200000);               // 19,200,000
    bfu*  B2      = (bfu*) (ws + 38400000);               // 19,200,000
    int2* bedge   = (int2*)(ws + 57600000);               // 9,600,000 (bucket-sorted)
    int2* sedge   = (int2*)(ws + 67200000);               // 9,600,000 (row-sorted)
    int*  gcounts = (int*) (ws + 76800000);               // 600,064
    int*  gscan   = (int*) (ws + 77400064);               // 600,064
    int*  bsum    = (int*) (ws + 78000128);               // 2,560
    int*  bsumoff = (int*) (ws + 78002688);               // 2,560
    int*  boff    = (int*) (ws + 78005248);               // 2,348
    int*  off     = (int*) (ws + 78007596);               // 600,064 (ends ~78.6 MB)

    const int BLK = 256;
    long long n4 = ((long long)N_NODES * DIM) >> 2;
    int convGrid = (int)((n4 + BLK - 1) / BLK);
    int gatherGrid = (N_NODES / 2 * 64) / BLK;            // 18750 blocks (75000 waves)
    int outMainGrid = (2 * NB * 64) / BLK;
    int outTailGrid = (NB + KNOW * DIM + BLK - 1) / BLK;

    // h0 -> bf16 table
    k_conv0<<<convGrid, BLK, 0, stream>>>(stu, exer, B0);

    // two-level counting sort (all writes dense)
    k_count<<<PB, 1024, 0, stream>>>(erow, gcounts);
    k_scan1<<<NSB, 256, 0, stream>>>(gcounts, gscan, bsum);
    k_scan2<<<1, 1024, 0, stream>>>(bsum, bsumoff);
    k_scan3<<<NSB, 256, 0, stream>>>(gscan, bsumoff, boff);
    k_place<<<PB, 1024, 0, stream>>>(erow, ecol, eval, gscan, bedge);
    k_sort <<<NBUCK, 512, 0, stream>>>(boff, bedge, sedge, off);

    // layers 1,2
    k_gather2<<<gatherGrid, BLK, 0, stream>>>(off, sedge, B0, B1);
    k_gather2<<<gatherGrid, BLK, 0, stream>>>(off, sedge, B1, B2);

    // layer 3 fused into outputs
    k_out_main<<<outMainGrid, BLK, 0, stream>>>(sid, eid, off, sedge, stu, exer, B1, B2, out);
    k_out_tail<<<outTailGrid, BLK, 0, stream>>>(eid, disc, know, out);
}

// Round 11
// 112.217 us; speedup vs baseline: 1.3815x; 1.0751x over previous
//
#include <hip/hip_runtime.h>

// LightGCN extractor, round 11:
//  - build: R8 two-level counting sort (all global writes dense) - unchanged
//  - gathers: block stages its 16 rows' edge records into LDS (dense coalesced,
//    records are contiguous after row-sort), then 4 rows/wave with 16-lane
//    groups; each lane covers 4 dims via one 8B load -> 0.25 VMEM instr/edge
//  - layer 3 fused into output kernel (R8 version)
//  NOTE: float atomicAdd on __shared__ is a slow generic path (~8000cy, R7) - avoid.

#define STU 100000
#define EXER 50000
#define KNOW 123
#define DIM 64
#define N_NODES 150000
#define N_EDGES 1200000
#define NB 8192
#define BR 256                 // rows per bucket
#define NBUCK 586              // ceil(150000/256)
#define PB 256                 // partition blocks
#define EPB 4688               // ceil(N_EDGES/PB)
#define NSB 586                // scan blocks over NBUCK*PB = 150016
#define SCAP 3072              // max edges per bucket (mean 2048)
#define RPB 16                 // rows per gather block
#define RCAP 512               // record staging cap (sum of 16 Poisson(8) ~ 128)

typedef unsigned short bfu;

__device__ __forceinline__ bfu f2bf(float f) {
    unsigned int u = __float_as_uint(f);
    unsigned int r = (u + 0x7FFFu + ((u >> 16) & 1u)) >> 16;   // RNE
    return (bfu)r;
}
__device__ __forceinline__ float bf2f(bfu h) {
    return __uint_as_float((unsigned int)h << 16);
}

// ---- h0 concat -> bf16 table ----
__global__ void k_conv0(const float* __restrict__ stu, const float* __restrict__ exer,
                        bfu* __restrict__ b0) {
    long long i = (long long)blockIdx.x * blockDim.x + threadIdx.x;  // float4 index
    long long n4 = ((long long)N_NODES * DIM) >> 2;
    if (i >= n4) return;
    long long stu4 = ((long long)STU * DIM) >> 2;
    float4 v = (i < stu4) ? ((const float4*)stu)[i]
                          : ((const float4*)exer)[i - stu4];
    ushort4 o;
    o.x = f2bf(v.x); o.y = f2bf(v.y); o.z = f2bf(v.z); o.w = f2bf(v.w);
    ((ushort4*)b0)[i] = o;
}

// ---- bucket counts: gcounts[bucket*PB + block] ----
__global__ __launch_bounds__(1024) void k_count(const int* __restrict__ erow,
                                                int* __restrict__ gcounts) {
    __shared__ int cnt[NBUCK];
    for (int i = threadIdx.x; i < NBUCK; i += 1024) cnt[i] = 0;
    __syncthreads();
    int b = blockIdx.x;
    long long s = (long long)b * EPB;
    long long e = s + EPB; if (e > N_EDGES) e = N_EDGES;
    for (long long k = s + threadIdx.x; k < e; k += 1024)
        atomicAdd(&cnt[__builtin_nontemporal_load(&erow[k]) >> 8], 1);
    __syncthreads();
    for (int i = threadIdx.x; i < NBUCK; i += 1024) gcounts[i * PB + b] = cnt[i];
}

// ---- hierarchical exclusive scan over 150016 ints ----
__global__ void k_scan1(const int* __restrict__ gin, int* __restrict__ gout,
                        int* __restrict__ bsum) {
    __shared__ int s[256];
    int i = blockIdx.x * 256 + threadIdx.x;
    int v = gin[i];
    s[threadIdx.x] = v;
    __syncthreads();
    for (int o = 1; o < 256; o <<= 1) {
        int x = (threadIdx.x >= o) ? s[threadIdx.x - o] : 0;
        __syncthreads();
        s[threadIdx.x] += x;
        __syncthreads();
    }
    gout[i] = s[threadIdx.x] - v;
    if (threadIdx.x == 255) bsum[blockIdx.x] = s[255];
}

__global__ void k_scan2(const int* __restrict__ bsum, int* __restrict__ bsumoff) {
    __shared__ int s[1024];
    int t = threadIdx.x;
    int v = (t < NSB) ? bsum[t] : 0;
    s[t] = v;
    __syncthreads();
    for (int o = 1; o < 1024; o <<= 1) {
        int x = (t >= o) ? s[t - o] : 0;
        __syncthreads();
        s[t] += x;
        __syncthreads();
    }
    if (t < NSB) bsumoff[t] = s[t] - v;
}

__global__ void k_scan3(int* __restrict__ gout, const int* __restrict__ bsumoff,
                        int* __restrict__ boff) {
    int i = blockIdx.x * 256 + threadIdx.x;
    int v = gout[i] + bsumoff[i >> 8];
    gout[i] = v;
    if ((i & 255) == 0) boff[i >> 8] = v;   // PB==256: bucket start
    if (i == 0) boff[NBUCK] = N_EDGES;
}

// ---- place: block-local LDS counting sort by bucket, dense run writes ----
__global__ __launch_bounds__(1024) void k_place(const int* __restrict__ erow,
                                                const int* __restrict__ ecol,
                                                const float* __restrict__ eval,
                                                const int* __restrict__ gscan,
                                                int2* __restrict__ bedge) {
    __shared__ int2 staged[EPB];            // 37504 B
    __shared__ unsigned short sbkt[EPB];    // 9376 B
    __shared__ int lbase[NBUCK];
    __shared__ int lcur[NBUCK];
    __shared__ int gbase[NBUCK];
    __shared__ int stmp[1024];
    int b = blockIdx.x, tid = threadIdx.x;
    for (int i = tid; i < NBUCK; i += 1024) lcur[i] = 0;
    __syncthreads();
    long long s = (long long)b * EPB;
    long long e = s + EPB; if (e > N_EDGES) e = N_EDGES;
    int n = (int)(e - s);
    for (int k = tid; k < n; k += 1024)
        atomicAdd(&lcur[__builtin_nontemporal_load(&erow[s + k]) >> 8], 1);
    __syncthreads();
    int v = (tid < NBUCK) ? lcur[tid] : 0;
    stmp[tid] = v;
    __syncthreads();
    for (int o = 1; o < 1024; o <<= 1) {
        int x = (tid >= o) ? stmp[tid - o] : 0;
        __syncthreads();
        stmp[tid] += x;
        __syncthreads();
    }
    if (tid < NBUCK) { lbase[tid] = stmp[tid] - v; lcur[tid] = stmp[tid] - v; }
    for (int i = tid; i < NBUCK; i += 1024) gbase[i] = gscan[i * PB + b];
    __syncthreads();
    for (int k = tid; k < n; k += 1024) {
        int r = __builtin_nontemporal_load(&erow[s + k]);
        int c = __builtin_nontemporal_load(&ecol[s + k]);
        float vv = __builtin_nontemporal_load(&eval[s + k]);
        int bk = r >> 8;
        int p = atomicAdd(&lcur[bk], 1);
        staged[p] = make_int2((r & 255) | (c << 8), __float_as_int(vv));
        sbkt[p] = (unsigned short)bk;
    }
    __syncthreads();
    for (int t = tid; t < n; t += 1024) {
        int bk = sbkt[t];
        bedge[gbase[bk] + (t - lbase[bk])] = staged[t];
    }
}

// ---- per-bucket LDS counting sort by row -> row-sorted edges + off[] ----
__global__ __launch_bounds__(512) void k_sort(const int* __restrict__ boff,
                                              const int2* __restrict__ bedge,
                                              int2* __restrict__ sedge,
                                              int* __restrict__ off) {
    __shared__ int2 st[SCAP];      // 24 KB
    __shared__ int2 st2[SCAP];     // 24 KB
    __shared__ int hist[BR];
    __shared__ int cur[BR];
    __shared__ int stmp[512];
    int b = blockIdx.x, tid = threadIdx.x;
    int s = boff[b], e = boff[b + 1];
    int n = e - s; if (n > SCAP) n = SCAP;   // statistically unreachable
    for (int i = tid; i < BR; i += 512) hist[i] = 0;
    __syncthreads();
    for (int t = tid; t < n; t += 512) {
        int2 ev = bedge[s + t];
        st[t] = ev;
        atomicAdd(&hist[ev.x & 255], 1);
    }
    __syncthreads();
    int v = (tid < BR) ? hist[tid] : 0;
    stmp[tid] = v;
    __syncthreads();
    for (int o = 1; o < 512; o <<= 1) {
        int x = (tid >= o) ? stmp[tid - o] : 0;
        __syncthreads();
        stmp[tid] += x;
        __syncthreads();
    }
    if (tid < BR) {
        int ex = stmp[tid] - v;
        cur[tid] = ex;
        off[b * BR + tid] = s + ex;    // global row offset
    }
    __syncthreads();
    for (int t = tid; t < n; t += 512) {
        int2 ev = st[t];
        int p = atomicAdd(&cur[ev.x & 255], 1);
        st2[p] = make_int2((unsigned)ev.x >> 8, ev.y);   // (col, valbits)
    }
    __syncthreads();
    for (int t = tid; t < n; t += 512) sedge[s + t] = st2[t];
}

// ---- gather layer: 16 rows/block, records LDS-staged, 4 rows/wave ----
__global__ __launch_bounds__(256) void k_gather16(const int* __restrict__ off,
                                                  const int2* __restrict__ sedge,
                                                  const bfu* __restrict__ h,
                                                  bfu* __restrict__ out) {
    __shared__ int2 rec[RCAP];
    __shared__ int soff[RPB + 1];
    int tid = threadIdx.x;
    int base = blockIdx.x * RPB;                 // 9375 blocks x 16 rows = 150000
    if (tid <= RPB) soff[tid] = off[base + tid];
    __syncthreads();
    int s0 = soff[0];
    int n = soff[RPB] - s0; if (n > RCAP) n = RCAP;   // unreachable
    for (int i = tid; i < n; i += 256) rec[i] = sedge[s0 + i];   // dense coalesced
    __syncthreads();

    int wv = tid >> 6, grp = (tid >> 4) & 3, l16 = tid & 15;
    int lr = wv * 4 + grp;                        // local row 0..15
    int rs = soff[lr] - s0, re = soff[lr + 1] - s0;
    const uint2* h2 = (const uint2*)h;            // row = 16 x uint2 (128B)
    float a0 = 0.f, a1 = 0.f, a2 = 0.f, a3 = 0.f;
    for (int k = rs; k < re; k += 8) {
        int2 ev[8]; float wg[8];
#pragma unroll
        for (int q = 0; q < 8; q++) {
            int idx = (k + q < re) ? (k + q) : rs;
            ev[q] = rec[idx];
            wg[q] = (k + q < re) ? __int_as_float(ev[q].y) : 0.f;
        }
        uint2 hv[8];
#pragma unroll
        for (int q = 0; q < 8; q++) hv[q] = h2[(size_t)ev[q].x * 16 + l16];
#pragma unroll
        for (int q = 0; q < 8; q++) {
            a0 += wg[q] * __uint_as_float(hv[q].x << 16);
            a1 += wg[q] * __uint_as_float(hv[q].x & 0xffff0000u);
            a2 += wg[q] * __uint_as_float(hv[q].y << 16);
            a3 += wg[q] * __uint_as_float(hv[q].y & 0xffff0000u);
        }
    }
    uint2 o;
    o.x = (unsigned)f2bf(a0) | ((unsigned)f2bf(a1) << 16);
    o.y = (unsigned)f2bf(a2) | ((unsigned)f2bf(a3) << 16);
    ((uint2*)out)[(size_t)(base + lr) * 16 + l16] = o;
}

// ---- outputs: layer-3 gather over B2 fused, only the 16K needed rows ----
// out layout: [0,524288) student_ts | [524288,1048576) diff_ts
//             [1048576,1056768) disc | [1056768,1064640) know
__global__ void k_out_main(const int* __restrict__ sid, const int* __restrict__ eid,
                           const int* __restrict__ off, const int2* __restrict__ sedge,
                           const float* __restrict__ stu, const float* __restrict__ exer,
                           const bfu* __restrict__ B1, const bfu* __restrict__ B2,
                           float* __restrict__ out) {
    int w = (blockIdx.x * blockDim.x + threadIdx.x) >> 6;
    int lane = threadIdx.x & 63;
    if (w >= 2 * NB) return;
    int wu = __builtin_amdgcn_readfirstlane(w);
    int r;
    long long obase;
    if (wu < NB) { r = sid[wu];            obase = (long long)wu * 64; }
    else         { r = STU + eid[wu - NB]; obase = 524288 + (long long)(wu - NB) * 64; }
    int ru = __builtin_amdgcn_readfirstlane(r);
    long long rb = (long long)ru * 64 + lane;
    float h0 = (ru < STU) ? stu[rb] : exer[rb - (long long)STU * 64];
    float ssum = h0 + bf2f(B1[rb]) + bf2f(B2[rb]);
    int st = off[ru], en = off[ru + 1];
    float g = 0.f;
    int k = st;
    for (; k + 8 <= en; k += 8) {
        int2 ev[8];
#pragma unroll
        for (int j = 0; j < 8; j++) ev[j] = sedge[k + j];
        float a[8];
#pragma unroll
        for (int j = 0; j < 8; j++) a[j] = bf2f(B2[(size_t)ev[j].x * DIM + lane]);
#pragma unroll
        for (int j = 0; j < 8; j++) g += __int_as_float(ev[j].y) * a[j];
    }
    for (; k < en; k++) {
        int2 ev = sedge[k];
        g += __int_as_float(ev.y) * bf2f(B2[(size_t)ev.x * DIM + lane]);
    }
    out[obase + lane] = 0.25f * (ssum + g);
}

__global__ void k_out_tail(const int* __restrict__ eid, const float* __restrict__ disc,
                           const float* __restrict__ know, float* __restrict__ out) {
    int i = blockIdx.x * blockDim.x + threadIdx.x;
    if (i < NB) out[1048576 + i] = disc[eid[i]];
    else if (i < NB + KNOW * DIM) out[1056768 + (i - NB)] = know[i - NB];
}

extern "C" void kernel_launch(void* const* d_in, const int* in_sizes, int n_in,
                              void* d_out, int out_size, void* d_ws, size_t ws_size,
                              hipStream_t stream) {
    const int*   sid  = (const int*)d_in[0];
    const int*   eid  = (const int*)d_in[1];
    const int*   erow = (const int*)d_in[3];
    const int*   ecol = (const int*)d_in[4];
    const float* eval = (const float*)d_in[5];
    const float* stu  = (const float*)d_in[6];
    const float* exer = (const float*)d_in[7];
    const float* disc = (const float*)d_in[8];
    const float* know = (const float*)d_in[9];
    float* out = (float*)d_out;

    char* ws = (char*)d_ws;
    bfu*  B0      = (bfu*) (ws);                          // 19,200,000
    bfu*  B1      = (bfu*) (ws + 19200000);               // 19,200,000
    bfu*  B2      = (bfu*) (ws + 38400000);               // 19,200,000
    int2* bedge   = (int2*)(ws + 57600000);               // 9,600,000 (bucket-sorted)
    int2* sedge   = (int2*)(ws + 67200000);               // 9,600,000 (row-sorted)
    int*  gcounts = (int*) (ws + 76800000);               // 600,064
    int*  gscan   = (int*) (ws + 77400064);               // 600,064
    int*  bsum    = (int*) (ws + 78000128);               // 2,560
    int*  bsumoff = (int*) (ws + 78002688);               // 2,560
    int*  boff    = (int*) (ws + 78005248);               // 2,348
    int*  off     = (int*) (ws + 78007596);               // 600,064 (ends ~78.6 MB)

    const int BLK = 256;
    long long n4 = ((long long)N_NODES * DIM) >> 2;
    int convGrid = (int)((n4 + BLK - 1) / BLK);
    int gatherGrid = N_NODES / RPB;                       // 9375 blocks
    int outMainGrid = (2 * NB * 64) / BLK;
    int outTailGrid = (NB + KNOW * DIM + BLK - 1) / BLK;

    // h0 -> bf16 table
    k_conv0<<<convGrid, BLK, 0, stream>>>(stu, exer, B0);

    // two-level counting sort (all writes dense)
    k_count<<<PB, 1024, 0, stream>>>(erow, gcounts);
    k_scan1<<<NSB, 256, 0, stream>>>(gcounts, gscan, bsum);
    k_scan2<<<1, 1024, 0, stream>>>(bsum, bsumoff);
    k_scan3<<<NSB, 256, 0, stream>>>(gscan, bsumoff, boff);
    k_place<<<PB, 1024, 0, stream>>>(erow, ecol, eval, gscan, bedge);
    k_sort <<<NBUCK, 512, 0, stream>>>(boff, bedge, sedge, off);

    // layers 1,2
    k_gather16<<<gatherGrid, BLK, 0, stream>>>(off, sedge, B0, B1);
    k_gather16<<<gatherGrid, BLK, 0, stream>>>(off, sedge, B1, B2);

    // layer 3 fused into outputs
    k_out_main<<<outMainGrid, BLK, 0, stream>>>(sid, eid, off, sedge, stu, exer, B1, B2, out);
    k_out_tail<<<outTailGrid, BLK, 0, stream>>>(eid, disc, know, out);
}